// Round 1
// baseline (5619.963 us; speedup 1.0000x reference)
//
#include <hip/hip_runtime.h>

// PoseSPDecoderKT — fp32 baseline (round 0, correctness-first).
// All heavy stages are per-batch im2col GEMMs on the fp32 VALU (no fp32 MFMA
// on CDNA4). Precision: fully fp32 because rotation_6d_to_matrix amplifies
// pose6d errors by up to ~1000x (min ||a2p|| ~ 1e-3 over 21504 samples).

__constant__ int KPAR_C[21] = {0,0,0,1,2,3,4,5,6,7,8,9,9,9,12,13,14,16,17,18,19};

// ---------------- K0: weight transpose to k-major (k = kk*512 + c) ----------
// dst[(kk*512+c)*512 + w] = src[w*1536 + c*3 + kk]
__global__ __launch_bounds__(256)
void kw_transpose(const float* __restrict__ conv1_w,
                  const float* __restrict__ up_w,
                  float* __restrict__ dst) {
  const int PER = 512 * 512 * 3;  // 786432 = 3 * 2^18
  int gid = blockIdx.x * 256 + threadIdx.x;
  if (gid >= 4 * PER) return;
  int wsel = gid / PER;
  int d = gid - wsel * PER;
  int w = d & 511;
  int c = (d >> 9) & 511;
  int kk = d >> 18;
  const float* src = (wsel == 0) ? conv1_w : (up_w + (size_t)(wsel - 1) * PER);
  dst[(size_t)wsel * PER + d] = src[(size_t)w * 1536 + c * 3 + kk];
}

// ---------------- K1: conv1 (edge-pad, k=3) + token-mix, fused per batch ----
// GEMM1: h1[t,w] = relu(sum_{kk,c} w1[w,c,kk] * x[b, clamp(t-1+kk), c] + b1[w])
// GEMM2: h2[s,w] = relu(sum_t tok_w[s,t] * h1[t,w] + tok_b[s])
// h1 (64x512 f32 = 128KiB) lives in LDS between the two GEMMs.
__global__ __launch_bounds__(512)
void k1_conv_tok(const float* __restrict__ x,        // (1024,64,512)
                 const float* __restrict__ w1t,      // (1536,512) k-major
                 const float* __restrict__ conv1_b,  // (512)
                 const float* __restrict__ tok_w,    // (64,64)
                 const float* __restrict__ tok_b,    // (64)
                 float* __restrict__ h2out) {        // (1024,64,512)
  __shared__ float h1[64 * 512];     // 128 KiB
  __shared__ float stg[4608];        // atile[8][64] + btile[8][512]; reused as twt[64][64]
  float* atile = stg;
  float* btile = stg + 512;
  float* twt = stg;

  const int tid = threadIdx.x;
  const int b = blockIdx.x;
  const int tm = tid >> 6;   // 0..7 (wave-uniform -> A reads broadcast)
  const int tn = tid & 63;   // 0..63 (consecutive cols -> conflict-free B reads)
  const int lk = tid & 7;
  const int lt = tid >> 3;
  const float* xb = x + (size_t)b * (64 * 512);

  float acc[8][8];
#pragma unroll
  for (int i = 0; i < 8; ++i)
#pragma unroll
    for (int j = 0; j < 8; ++j) acc[i][j] = 0.f;

  for (int kb = 0; kb < 1536; kb += 8) {
    const int kk = kb >> 9;
    const int cbase = kb & 511;
    // stage A: atile[k][t] = x[b, clamp(t-1+kk), cbase+k]
    {
      int tt = lt - 1 + kk;
      tt = tt < 0 ? 0 : (tt > 63 ? 63 : tt);
      atile[lk * 64 + lt] = xb[tt * 512 + cbase + lk];
    }
    // stage B: btile[k][w] = w1t[(kb+k)*512 + w]
    {
      const float4* bsrc = (const float4*)(w1t + (size_t)kb * 512);
      float4* bdst = (float4*)btile;
      bdst[tid] = bsrc[tid];
      bdst[tid + 512] = bsrc[tid + 512];
    }
    __syncthreads();
#pragma unroll
    for (int k = 0; k < 8; ++k) {
      float a[8], bv[8];
#pragma unroll
      for (int i = 0; i < 8; ++i) a[i] = atile[k * 64 + tm * 8 + i];
#pragma unroll
      for (int j = 0; j < 8; ++j) bv[j] = btile[k * 512 + tn + 64 * j];
#pragma unroll
      for (int i = 0; i < 8; ++i)
#pragma unroll
        for (int j = 0; j < 8; ++j) acc[i][j] = fmaf(a[i], bv[j], acc[i][j]);
    }
    __syncthreads();
  }
  // bias + relu -> h1 (LDS)
#pragma unroll
  for (int j = 0; j < 8; ++j) {
    const int w = tn + 64 * j;
    const float bias = conv1_b[w];
#pragma unroll
    for (int i = 0; i < 8; ++i) {
      float v = acc[i][j] + bias;
      h1[(tm * 8 + i) * 512 + w] = v > 0.f ? v : 0.f;
    }
  }
  __syncthreads();
  // stage twt[t][s] = tok_w[s][t] (overwrites atile/btile region)
#pragma unroll
  for (int r = 0; r < 8; ++r) {
    int idx = r * 512 + tid;
    twt[(idx & 63) * 64 + (idx >> 6)] = tok_w[idx];
  }
  __syncthreads();

  float a2[8][8];
#pragma unroll
  for (int i = 0; i < 8; ++i)
#pragma unroll
    for (int j = 0; j < 8; ++j) a2[i][j] = 0.f;
  for (int t = 0; t < 64; ++t) {
    float a[8], bv[8];
#pragma unroll
    for (int i = 0; i < 8; ++i) a[i] = twt[t * 64 + tm * 8 + i];
#pragma unroll
    for (int j = 0; j < 8; ++j) bv[j] = h1[t * 512 + tn + 64 * j];
#pragma unroll
    for (int i = 0; i < 8; ++i)
#pragma unroll
      for (int j = 0; j < 8; ++j) a2[i][j] = fmaf(a[i], bv[j], a2[i][j]);
  }
  float* outb = h2out + (size_t)b * (64 * 512);
#pragma unroll
  for (int i = 0; i < 8; ++i) {
    const int s = tm * 8 + i;
    const float bias = tok_b[s];
#pragma unroll
    for (int j = 0; j < 8; ++j) {
      float v = a2[i][j] + bias;
      outb[s * 512 + tn + 64 * j] = v > 0.f ? v : 0.f;
    }
  }
}

// ---------------- K2/3/4: interp(SIN->SOUT) + conv(k=3, edge pad) -----------
// A-tile staged per k-tile with the interp computed on the fly (input stays
// L2-resident; LDS only 18KB -> 4 blocks/CU).
template <int SOUT, int SIN, int RPT, bool RELU>
__global__ __launch_bounds__(512)
void k_up(const float* __restrict__ in,    // (B, SIN, 512)
          const float* __restrict__ wt,    // (1536,512) k-major
          const float* __restrict__ bias,  // (512)
          float* __restrict__ out) {       // (B, SOUT, 512)
  __shared__ float atile[8 * 64];
  __shared__ float btile[8 * 512];
  const int tid = threadIdx.x;
  const int b = blockIdx.x;
  const int tm = tid >> 6, tn = tid & 63;
  const int lk = tid & 7, lt = tid >> 3;
  const float* inb = in + (size_t)b * (SIN * 512);
  const float scale = (float)SIN / (float)SOUT;

  float acc[RPT][8];
#pragma unroll
  for (int i = 0; i < RPT; ++i)
#pragma unroll
    for (int j = 0; j < 8; ++j) acc[i][j] = 0.f;

  for (int kb = 0; kb < 1536; kb += 8) {
    const int kk = kb >> 9;
    const int cbase = kb & 511;
    // stage A: atile[k][t] = g[clamp(t-1+kk), cbase+k], g = interp(in)
    {
      int s = lt - 1 + kk;
      s = s < 0 ? 0 : (s > SOUT - 1 ? SOUT - 1 : s);
      float coords = ((float)s + 0.5f) * scale - 0.5f;
      coords = fminf(fmaxf(coords, 0.f), (float)(SIN - 1));
      float fl = floorf(coords);
      int lo = (int)fl;
      int hi = lo + 1 < SIN ? lo + 1 : SIN - 1;
      float wv = coords - fl;
      atile[lk * 64 + lt] = inb[lo * 512 + cbase + lk] * (1.f - wv) +
                            inb[hi * 512 + cbase + lk] * wv;
    }
    {
      const float4* bsrc = (const float4*)(wt + (size_t)kb * 512);
      float4* bdst = (float4*)btile;
      bdst[tid] = bsrc[tid];
      bdst[tid + 512] = bsrc[tid + 512];
    }
    __syncthreads();
#pragma unroll
    for (int k = 0; k < 8; ++k) {
      float a[RPT], bv[8];
#pragma unroll
      for (int i = 0; i < RPT; ++i) a[i] = atile[k * 64 + tm + 8 * i];
#pragma unroll
      for (int j = 0; j < 8; ++j) bv[j] = btile[k * 512 + tn + 64 * j];
#pragma unroll
      for (int i = 0; i < RPT; ++i)
#pragma unroll
        for (int j = 0; j < 8; ++j) acc[i][j] = fmaf(a[i], bv[j], acc[i][j]);
    }
    __syncthreads();
  }
  float* outb = out + (size_t)b * (SOUT * 512);
#pragma unroll
  for (int j = 0; j < 8; ++j) {
    const int w = tn + 64 * j;
    const float bb = bias[w];
#pragma unroll
    for (int i = 0; i < RPT; ++i) {
      const int r = tm + 8 * i;
      if (r < SOUT) {
        float v = acc[i][j] + bb;
        if (RELU) v = v > 0.f ? v : 0.f;
        outb[r * 512 + w] = v;
      }
    }
  }
}

// ---------------- K5: mean over T, LayerNorm over W, beta head --------------
__global__ __launch_bounds__(256)
void k_beta(const float* __restrict__ h,  // (B,22,512)
            const float* __restrict__ ln_g, const float* __restrict__ ln_b,
            const float* __restrict__ beta_w,  // (512,10)
            const float* __restrict__ beta_b,  // (10)
            float* __restrict__ out) {         // (B,10)
  __shared__ float nbuf[512];
  __shared__ float red[32];
  __shared__ float part[160];
  const int tid = threadIdx.x;
  const int b = blockIdx.x;
  const float* hb = h + (size_t)b * (22 * 512);
  float m0 = 0.f, m1 = 0.f;
  for (int t = 0; t < 22; ++t) {
    m0 += hb[t * 512 + tid];
    m1 += hb[t * 512 + tid + 256];
  }
  m0 *= (1.f / 22.f);
  m1 *= (1.f / 22.f);
  float s = m0 + m1, sq = m0 * m0 + m1 * m1;
  for (int off = 32; off > 0; off >>= 1) {
    s += __shfl_down(s, off);
    sq += __shfl_down(sq, off);
  }
  const int lane = tid & 63, wid = tid >> 6;
  if (lane == 0) { red[wid] = s; red[8 + wid] = sq; }
  __syncthreads();
  if (tid == 0) {
    float S = red[0] + red[1] + red[2] + red[3];
    float Q = red[8] + red[9] + red[10] + red[11];
    float mu = S * (1.f / 512.f);
    float var = Q * (1.f / 512.f) - mu * mu;
    red[16] = mu;
    red[17] = 1.f / sqrtf(var + 1e-5f);
  }
  __syncthreads();
  const float mu = red[16], rs = red[17];
  nbuf[tid] = (m0 - mu) * rs * ln_g[tid] + ln_b[tid];
  nbuf[tid + 256] = (m1 - mu) * rs * ln_g[tid + 256] + ln_b[tid + 256];
  __syncthreads();
  if (tid < 160) {
    const int o = tid >> 4, l = tid & 15;
    float p = 0.f;
    for (int w = l; w < 512; w += 16) p += nbuf[w] * beta_w[w * 10 + o];
    part[tid] = p;
  }
  __syncthreads();
  if (tid < 10) {
    float p = beta_b[tid];
#pragma unroll
    for (int l = 0; l < 16; ++l) p += part[tid * 16 + l];
    out[(size_t)b * 10 + tid] = p;
  }
}

// ---------------- K6: per-joint MLP + 6d->rotmat ----------------------------
// Block = (one joint j, 16 batches). 512 threads; each thread owns one hidden
// column h=tid for all 16 batches (pw1[j] column loaded once per c, reused 16x).
__global__ __launch_bounds__(512)
void k_pose(const float* __restrict__ h,    // (B,22,512)
            const float* __restrict__ pw1,  // (21,1024,512)
            const float* __restrict__ pb1,  // (21,512)
            const float* __restrict__ pw2,  // (21,512,6)
            const float* __restrict__ pb2,  // (21,6)
            float* __restrict__ out) {      // pose6d @0, rotmat @129024
  __shared__ float feat[16 * 1028];  // stride 1028 -> 16B-aligned float4 rows
  __shared__ float hid[16 * 513];    // stride 513 -> conflict-free strided reads
  __shared__ float p6[16 * 6];
  const int tid = threadIdx.x;
  const int j = blockIdx.y;
  const int bb0 = blockIdx.x * 16;
  const int par = KPAR_C[j];

  for (int idx = tid; idx < 16 * 1024; idx += 512) {
    const int gb = idx >> 10;
    const int c = idx & 1023;
    const int row = (c < 512) ? (j + 1) : par;
    feat[gb * 1028 + c] = h[((size_t)(bb0 + gb) * 22 + row) * 512 + (c & 511)];
  }
  __syncthreads();

  const float* w1 = pw1 + (size_t)j * (1024 * 512);
  float acc[16];
#pragma unroll
  for (int gb = 0; gb < 16; ++gb) acc[gb] = 0.f;

  for (int c = 0; c < 1024; c += 4) {
    float wa[4];
#pragma unroll
    for (int u = 0; u < 4; ++u) wa[u] = w1[(size_t)(c + u) * 512 + tid];
#pragma unroll
    for (int gb = 0; gb < 16; ++gb) {
      const float4 f = *(const float4*)&feat[gb * 1028 + c];
      acc[gb] = fmaf(f.x, wa[0], acc[gb]);
      acc[gb] = fmaf(f.y, wa[1], acc[gb]);
      acc[gb] = fmaf(f.z, wa[2], acc[gb]);
      acc[gb] = fmaf(f.w, wa[3], acc[gb]);
    }
  }
  const float bias1 = pb1[(size_t)j * 512 + tid];
#pragma unroll
  for (int gb = 0; gb < 16; ++gb) {
    float v = acc[gb] + bias1;
    hid[gb * 513 + tid] = v > 0.f ? v : 0.f;
  }
  __syncthreads();

  if (tid < 96) {
    const int gb = tid / 6;
    const int d = tid % 6;
    const float* w2 = pw2 + (size_t)j * (512 * 6) + d;
    float p = pb2[j * 6 + d];
    for (int hh = 0; hh < 512; ++hh) p = fmaf(hid[gb * 513 + hh], w2[hh * 6], p);
    p6[gb * 6 + d] = p;
    out[((size_t)(bb0 + gb) * 21 + j) * 6 + d] = p;
  }
  __syncthreads();
  if (tid < 16) {
    const int gb = tid;
    const float a1x = p6[gb * 6 + 0], a1y = p6[gb * 6 + 1], a1z = p6[gb * 6 + 2];
    const float a2x = p6[gb * 6 + 3], a2y = p6[gb * 6 + 4], a2z = p6[gb * 6 + 5];
    const float inv1 = 1.f / sqrtf(a1x * a1x + a1y * a1y + a1z * a1z);
    const float b1x = a1x * inv1, b1y = a1y * inv1, b1z = a1z * inv1;
    const float dot = b1x * a2x + b1y * a2y + b1z * a2z;
    const float px = a2x - dot * b1x, py = a2y - dot * b1y, pz = a2z - dot * b1z;
    const float inv2 = 1.f / sqrtf(px * px + py * py + pz * pz);
    const float b2x = px * inv2, b2y = py * inv2, b2z = pz * inv2;
    const float b3x = b1y * b2z - b1z * b2y;
    const float b3y = b1z * b2x - b1x * b2z;
    const float b3z = b1x * b2y - b1y * b2x;
    float* ro = out + 129024 + ((size_t)(bb0 + gb) * 21 + j) * 9;
    ro[0] = b1x; ro[1] = b1y; ro[2] = b1z;
    ro[3] = b2x; ro[4] = b2y; ro[5] = b2z;
    ro[6] = b3x; ro[7] = b3y; ro[8] = b3z;
  }
}

// ---------------- launch ----------------------------------------------------
extern "C" void kernel_launch(void* const* d_in, const int* in_sizes, int n_in,
                              void* d_out, int out_size, void* d_ws, size_t ws_size,
                              hipStream_t stream) {
  (void)in_sizes; (void)n_in; (void)out_size; (void)ws_size;
  const float* x       = (const float*)d_in[0];
  const float* conv1_w = (const float*)d_in[1];
  const float* conv1_b = (const float*)d_in[2];
  const float* tok_w   = (const float*)d_in[3];
  const float* tok_b   = (const float*)d_in[4];
  const float* up_w    = (const float*)d_in[5];
  const float* up_b    = (const float*)d_in[6];
  const float* ln_g    = (const float*)d_in[7];
  const float* ln_b    = (const float*)d_in[8];
  const float* beta_w  = (const float*)d_in[9];
  const float* beta_b  = (const float*)d_in[10];
  const float* pw1     = (const float*)d_in[11];
  const float* pb1     = (const float*)d_in[12];
  const float* pw2     = (const float*)d_in[13];
  const float* pb2     = (const float*)d_in[14];
  float* outp = (float*)d_out;
  float* ws = (float*)d_ws;

  const size_t PER = 512 * 512 * 3;
  float* w1t = ws;
  float* u0t = ws + PER;
  float* u1t = ws + 2 * PER;
  float* u2t = ws + 3 * PER;
  float* bufA = ws + 4 * PER;                     // (1024,64,512) then (1024,36,512)
  float* bufB = bufA + (size_t)1024 * 64 * 512;   // (1024,50,512) then (1024,22,512)
  // total ws need: 4*PER + 1024*64*512 + 1024*50*512 floats = 251,658,240 bytes

  kw_transpose<<<(int)((4 * PER + 255) / 256), 256, 0, stream>>>(conv1_w, up_w, ws);
  k1_conv_tok<<<1024, 512, 0, stream>>>(x, w1t, conv1_b, tok_w, tok_b, bufA);
  k_up<50, 64, 7, true><<<1024, 512, 0, stream>>>(bufA, u0t, up_b, bufB);
  k_up<36, 50, 5, true><<<1024, 512, 0, stream>>>(bufB, u1t, up_b + 512, bufA);
  k_up<22, 36, 3, false><<<1024, 512, 0, stream>>>(bufA, u2t, up_b + 1024, bufB);
  k_beta<<<1024, 256, 0, stream>>>(bufB, ln_g, ln_b, beta_w, beta_b, outp + 322560);
  k_pose<<<dim3(64, 21), 512, 0, stream>>>(bufB, pw1, pb1, pw2, pb2, outp);
}

// Round 2
// 1879.754 us; speedup vs baseline: 2.9897x; 2.9897x over previous
//
#include <hip/hip_runtime.h>

// PoseSPDecoderKT — round 1: split-bf16 MFMA for the four conv GEMMs.
// a = a_hi + a_lo (bf16 RNE split), 3 MFMA products per tile (drop lo*lo):
// relative error ~2^-18*sqrt-ish -> ~1e-5, vs 2e-2 threshold (fp32 showed 3.9e-3).
// LDS tiles are stored in EXACT MFMA fragment order (lane-major 16B chunks):
// all frag reads are ds_read_b128 at base+lane*16 -> conflict-free.
// k_pose / k_beta stay fp32 (rotation_6d_to_matrix amplifies pose6d error ~1e4x).

typedef unsigned short u16;
typedef unsigned short u16x4 __attribute__((ext_vector_type(4)));
typedef unsigned short u16x8 __attribute__((ext_vector_type(8)));
typedef float f32x4 __attribute__((ext_vector_type(4)));
typedef __bf16 bf16x8 __attribute__((ext_vector_type(8)));

__constant__ int KPAR_C[21] = {0,0,0,1,2,3,4,5,6,7,8,9,9,9,12,13,14,16,17,18,19};

__device__ __forceinline__ u16 bf16rne(float v) {
  unsigned b = __builtin_bit_cast(unsigned, v);
  return (u16)((b + 0x7fffu + ((b >> 16) & 1u)) >> 16);
}
__device__ __forceinline__ float bf16tof(u16 h) {
  unsigned b = ((unsigned)h) << 16;
  return __builtin_bit_cast(float, b);
}
__device__ __forceinline__ f32x4 mfma16(u16x8 a, u16x8 b, f32x4 c) {
  return __builtin_amdgcn_mfma_f32_16x16x32_bf16(
      __builtin_bit_cast(bf16x8, a), __builtin_bit_cast(bf16x8, b), c, 0, 0, 0);
}

// ---------------- kwprep: weights -> fragment-order split-bf16 tiles --------
// WF[L][nh][p][ks(48)][nf(16)][lane(64)][e(8)] u16.
// element <-> B[k][w]: w = nh*256+nf*16+(lane&15); k = ks*32+((lane>>4)<<2)+(e&3)+((e>>2)<<4)
// TWF[p][ks(2)][mf(4)][lane][e]: A-frags of tok_w: s = mf*16+(lane&15), t = k-mapping.
__global__ __launch_bounds__(256)
void kwprep(const float* __restrict__ conv1_w, const float* __restrict__ up_w,
            const float* __restrict__ tok_w, u16* __restrict__ WF, u16* __restrict__ TWF) {
  int idx = blockIdx.x * 256 + threadIdx.x;
  if (idx < 786432) {
    const int lane = idx & 63;
    int r = idx >> 6;
    const int nf = r & 15; r >>= 4;
    const int ks = r % 48; r /= 48;
    const int p = r & 1; r >>= 1;
    const int nh = r & 1;
    const int L = r >> 1;
    const float* Wsrc = (L == 0) ? conv1_w : (up_w + (size_t)(L - 1) * 786432);
    const int wcol = nh * 256 + nf * 16 + (lane & 15);
    u16x8 o;
#pragma unroll
    for (int e = 0; e < 8; ++e) {
      const int k = ks * 32 + ((lane >> 4) << 2) + (e & 3) + ((e >> 2) << 4);
      const int c = k & 511, kk = k >> 9;
      const float v = Wsrc[(size_t)wcol * 1536 + c * 3 + kk];
      const u16 h = bf16rne(v);
      o[e] = p ? bf16rne(v - bf16tof(h)) : h;
    }
    *(u16x8*)(WF + (size_t)idx * 8) = o;
  } else if (idx < 786432 + 1024) {
    const int i2 = idx - 786432;
    const int lane = i2 & 63;
    const int r = i2 >> 6;        // 0..15
    const int mf = r & 3;
    const int ks = (r >> 2) & 1;
    const int p = r >> 3;
    const int s = mf * 16 + (lane & 15);
    u16x8 o;
#pragma unroll
    for (int e = 0; e < 8; ++e) {
      const int t = ks * 32 + ((lane >> 4) << 2) + (e & 3) + ((e >> 2) << 4);
      const float v = tok_w[s * 64 + t];
      const u16 h = bf16rne(v);
      o[e] = p ? bf16rne(v - bf16tof(h)) : h;
    }
    *(u16x8*)(TWF + (size_t)i2 * 8) = o;
  }
}

// ---------------- conv GEMM (MFMA): C[t,w] = sum_k A[t,k]*B[k,w] -----------
// Block: 4 batches x 256 cols (nh half), 8 waves = 4 m-waves (1 batch each) x 2 n-waves.
// K = 1536 = 48 steps of 32. A = im2col(edge-clamped rows) of x (f32, split here)
// or of g planes (pre-split bf16). SLOT = padded row slot (mult of 16), ROWS = valid.
template <int SLOT, int ROWS, bool SRCF32, bool F32OUT, bool RELU>
__global__ __launch_bounds__(512, 2)
void conv_gemm(const float* __restrict__ xf,
               const u16* __restrict__ ghi, const u16* __restrict__ glo,
               const u16* __restrict__ wl,   // this layer's base in WF (u16 units)
               const float* __restrict__ bias,
               u16* __restrict__ ohi, u16* __restrict__ olo,
               float* __restrict__ of32) {
  constexpr int MFW = SLOT / 16;      // m-frags per wave
  constexpr int MFT = 4 * MFW;        // m-frags per block
  constexpr int ASL = (MFT + 7) / 8;  // A stage slots per wave
  __shared__ u16x8 Ald[2][2][MFT][64];
  __shared__ u16x8 Bld[2][2][16][64];

  const int tid = threadIdx.x, lane = tid & 63, w = tid >> 6;
  const int mw = w & 3, nw = w >> 2;
  const int nh = blockIdx.x;
  const int bb0 = blockIdx.y * 4;

  f32x4 acc[MFW][8];
#pragma unroll
  for (int m = 0; m < MFW; ++m)
#pragma unroll
    for (int n = 0; n < 8; ++n) acc[m][n] = (f32x4){0.f, 0.f, 0.f, 0.f};

  float4 sF[ASL][2];
  u16x8 sH[ASL], sL[ASL];
  u16x8 sB[4];

  auto LOADS = [&](int ks2) {
    const int kk2 = ks2 >> 4;
    const int c0 = (ks2 & 15) * 32 + ((lane >> 4) << 2);
#pragma unroll
    for (int si = 0; si < ASL; ++si) {
      const int f = w + si * 8;
      if (f < MFT) {
        const int bA = f / MFW, mfA = f % MFW;
        int t = mfA * 16 + (lane & 15) - 1 + kk2;
        t = t < 0 ? 0 : (t > ROWS - 1 ? ROWS - 1 : t);
        const size_t o = ((size_t)(bb0 + bA) * ROWS + t) * 512 + c0;
        if constexpr (SRCF32) {
          sF[si][0] = *(const float4*)(xf + o);
          sF[si][1] = *(const float4*)(xf + o + 16);
        } else {
          const u16x4 a = *(const u16x4*)(ghi + o);
          const u16x4 b = *(const u16x4*)(ghi + o + 16);
          const u16x4 c = *(const u16x4*)(glo + o);
          const u16x4 d = *(const u16x4*)(glo + o + 16);
          sH[si] = (u16x8){a[0], a[1], a[2], a[3], b[0], b[1], b[2], b[3]};
          sL[si] = (u16x8){c[0], c[1], c[2], c[3], d[0], d[1], d[2], d[3]};
        }
      }
    }
#pragma unroll
    for (int ci = 0; ci < 4; ++ci) {
      const int cch = w + ci * 8;
      const int p = cch >> 4, nf = cch & 15;
      sB[ci] = *(const u16x8*)(wl + ((size_t)(((nh * 2 + p) * 48 + ks2) * 16 + nf)) * 512 + lane * 8);
    }
  };

  auto WRITES = [&](int nb) {
#pragma unroll
    for (int si = 0; si < ASL; ++si) {
      const int f = w + si * 8;
      if (f < MFT) {
        u16x8 hv, lv;
        if constexpr (SRCF32) {
          float vv[8] = {sF[si][0].x, sF[si][0].y, sF[si][0].z, sF[si][0].w,
                         sF[si][1].x, sF[si][1].y, sF[si][1].z, sF[si][1].w};
#pragma unroll
          for (int e = 0; e < 8; ++e) {
            const u16 h = bf16rne(vv[e]);
            hv[e] = h;
            lv[e] = bf16rne(vv[e] - bf16tof(h));
          }
        } else {
          hv = sH[si];
          lv = sL[si];
        }
        Ald[nb][0][f][lane] = hv;
        Ald[nb][1][f][lane] = lv;
      }
    }
#pragma unroll
    for (int ci = 0; ci < 4; ++ci) {
      const int cch = w + ci * 8;
      Bld[nb][cch >> 4][cch & 15][lane] = sB[ci];
    }
  };

  LOADS(0);
  WRITES(0);
  __syncthreads();

  for (int ks = 0; ks < 48; ++ks) {
    const int buf = ks & 1;
    if (ks < 47) LOADS(ks + 1);
    u16x8 ah[MFW], al[MFW];
#pragma unroll
    for (int m = 0; m < MFW; ++m) {
      ah[m] = Ald[buf][0][mw * MFW + m][lane];
      al[m] = Ald[buf][1][mw * MFW + m][lane];
    }
#pragma unroll
    for (int n = 0; n < 8; ++n) {
      const u16x8 bh = Bld[buf][0][nw * 8 + n][lane];
      const u16x8 bl = Bld[buf][1][nw * 8 + n][lane];
#pragma unroll
      for (int m = 0; m < MFW; ++m) {
        acc[m][n] = mfma16(ah[m], bh, acc[m][n]);
        acc[m][n] = mfma16(ah[m], bl, acc[m][n]);
        acc[m][n] = mfma16(al[m], bh, acc[m][n]);
      }
    }
    if (ks < 47) WRITES(buf ^ 1);
    __syncthreads();
  }

  // epilogue: bias (+relu), mask t<ROWS, write split planes or f32
  const int b = bb0 + mw;
#pragma unroll
  for (int m = 0; m < MFW; ++m) {
#pragma unroll
    for (int n = 0; n < 8; ++n) {
      const int col = nh * 256 + nw * 128 + n * 16 + (lane & 15);
      const float bs = bias[col];
#pragma unroll
      for (int r = 0; r < 4; ++r) {
        const int t = m * 16 + ((lane >> 4) << 2) + r;
        if (t < ROWS) {
          float v = acc[m][n][r] + bs;
          if (RELU) v = fmaxf(v, 0.f);
          const size_t o = ((size_t)b * ROWS + t) * 512 + col;
          if constexpr (F32OUT) {
            of32[o] = v;
          } else {
            const u16 h = bf16rne(v);
            ohi[o] = h;
            olo[o] = bf16rne(v - bf16tof(h));
          }
        }
      }
    }
  }
}

// ---------------- tok_mix: h2 = relu(TW*h1 + tb), then interp 64->50 --------
// Block = (batch, c-half 256). h1 planes -> LDS f32; GEMM2 via MFMA with
// on-the-fly B-frag split; h2 back to LDS; interp rows; write g1 planes.
__global__ __launch_bounds__(512, 2)
void tok_mix(const u16* __restrict__ h1hi, const u16* __restrict__ h1lo,
             const u16* __restrict__ twf, const float* __restrict__ tok_b,
             u16* __restrict__ g1hi, u16* __restrict__ g1lo) {
  __shared__ float h1f[64][258];
  __shared__ u16x8 twl[2][2][4][64];  // [p][ks][mf][lane]
  __shared__ float tbl[64];
  const int tid = threadIdx.x, lane = tid & 63, w = tid >> 6;
  const int mw = w & 3, nw = w >> 2;
  const int b = blockIdx.y, ch = blockIdx.x;

  for (int i = tid; i < 1024; i += 512) ((u16x8*)twl)[i] = ((const u16x8*)twf)[i];
  if (tid < 64) tbl[tid] = tok_b[tid];
  for (int i = tid; i < 2048; i += 512) {
    const int t = i >> 5, c8 = (i & 31) * 8;
    const size_t o = ((size_t)b * 64 + t) * 512 + ch * 256 + c8;
    const u16x8 hv = *(const u16x8*)(h1hi + o);
    const u16x8 lv = *(const u16x8*)(h1lo + o);
#pragma unroll
    for (int e = 0; e < 8; ++e) h1f[t][c8 + e] = bf16tof(hv[e]) + bf16tof(lv[e]);
  }
  __syncthreads();

  f32x4 acc2[8];
#pragma unroll
  for (int n = 0; n < 8; ++n) acc2[n] = (f32x4){0.f, 0.f, 0.f, 0.f};
#pragma unroll
  for (int ksI = 0; ksI < 2; ++ksI) {
    const u16x8 ah = twl[0][ksI][mw][lane];
    const u16x8 al = twl[1][ksI][mw][lane];
    const int t0 = ksI * 32 + ((lane >> 4) << 2);
#pragma unroll
    for (int n = 0; n < 8; ++n) {
      const int c = nw * 128 + n * 16 + (lane & 15);
      u16x8 bh, bl;
#pragma unroll
      for (int e = 0; e < 8; ++e) {
        const float v = h1f[t0 + (e & 3) + ((e >> 2) << 4)][c];
        const u16 h = bf16rne(v);
        bh[e] = h;
        bl[e] = bf16rne(v - bf16tof(h));
      }
      acc2[n] = mfma16(ah, bh, acc2[n]);
      acc2[n] = mfma16(ah, bl, acc2[n]);
      acc2[n] = mfma16(al, bh, acc2[n]);
    }
  }
  __syncthreads();
  // h2 (relu) -> LDS (reuse h1f)
#pragma unroll
  for (int n = 0; n < 8; ++n) {
    const int c = nw * 128 + n * 16 + (lane & 15);
#pragma unroll
    for (int r = 0; r < 4; ++r) {
      const int s = mw * 16 + ((lane >> 4) << 2) + r;
      h1f[s][c] = fmaxf(acc2[n][r] + tbl[s], 0.f);
    }
  }
  __syncthreads();
  // interp 64 -> 50 + split + store
  const float scale = (float)(64.0 / 50.0);
  for (int i = tid; i < 50 * 256; i += 512) {
    const int s = i >> 8, c = i & 255;
    float coords = fminf(fmaxf(((float)s + 0.5f) * scale - 0.5f, 0.f), 63.f);
    const int lo = (int)floorf(coords);
    const int hi = lo + 1 < 64 ? lo + 1 : 63;
    const float wv = coords - (float)lo;
    const float v = h1f[lo][c] * (1.f - wv) + h1f[hi][c] * wv;
    const u16 h = bf16rne(v);
    const size_t o = ((size_t)b * 50 + s) * 512 + ch * 256 + c;
    g1hi[o] = h;
    g1lo[o] = bf16rne(v - bf16tof(h));
  }
}

// ---------------- ginterp: act planes (SIN rows) -> g planes (SOUT rows) ----
template <int SOUT, int SIN>
__global__ __launch_bounds__(256)
void ginterp(const u16* __restrict__ ahi, const u16* __restrict__ alo,
             u16* __restrict__ ghi, u16* __restrict__ glo) {
  const int idx = blockIdx.x * 256 + threadIdx.x;
  if (idx >= 1024 * SOUT * 64) return;
  const int ch = (idx & 63) * 8;
  const int s = (idx >> 6) % SOUT;
  const int b = (idx >> 6) / SOUT;
  const float scale = (float)((double)SIN / (double)SOUT);
  float coords = fminf(fmaxf(((float)s + 0.5f) * scale - 0.5f, 0.f), (float)(SIN - 1));
  const int lo = (int)floorf(coords);
  const int hi = lo + 1 < SIN ? lo + 1 : SIN - 1;
  const float wv = coords - (float)lo;
  const size_t olo_ = ((size_t)b * SIN + lo) * 512 + ch;
  const size_t ohi_ = ((size_t)b * SIN + hi) * 512 + ch;
  const u16x8 vh0 = *(const u16x8*)(ahi + olo_), vl0 = *(const u16x8*)(alo + olo_);
  const u16x8 vh1 = *(const u16x8*)(ahi + ohi_), vl1 = *(const u16x8*)(alo + ohi_);
  u16x8 oh, ol;
#pragma unroll
  for (int e = 0; e < 8; ++e) {
    const float v0 = bf16tof(vh0[e]) + bf16tof(vl0[e]);
    const float v1 = bf16tof(vh1[e]) + bf16tof(vl1[e]);
    const float v = v0 * (1.f - wv) + v1 * wv;
    const u16 h = bf16rne(v);
    oh[e] = h;
    ol[e] = bf16rne(v - bf16tof(h));
  }
  const size_t oo = ((size_t)b * SOUT + s) * 512 + ch;
  *(u16x8*)(ghi + oo) = oh;
  *(u16x8*)(glo + oo) = ol;
}

// ---------------- k_beta (unchanged from round 0) ---------------------------
__global__ __launch_bounds__(256)
void k_beta(const float* __restrict__ h, const float* __restrict__ ln_g,
            const float* __restrict__ ln_b, const float* __restrict__ beta_w,
            const float* __restrict__ beta_b, float* __restrict__ out) {
  __shared__ float nbuf[512];
  __shared__ float red[32];
  __shared__ float part[160];
  const int tid = threadIdx.x;
  const int b = blockIdx.x;
  const float* hb = h + (size_t)b * (22 * 512);
  float m0 = 0.f, m1 = 0.f;
  for (int t = 0; t < 22; ++t) {
    m0 += hb[t * 512 + tid];
    m1 += hb[t * 512 + tid + 256];
  }
  m0 *= (1.f / 22.f);
  m1 *= (1.f / 22.f);
  float s = m0 + m1, sq = m0 * m0 + m1 * m1;
  for (int off = 32; off > 0; off >>= 1) {
    s += __shfl_down(s, off);
    sq += __shfl_down(sq, off);
  }
  const int lane = tid & 63, wid = tid >> 6;
  if (lane == 0) { red[wid] = s; red[8 + wid] = sq; }
  __syncthreads();
  if (tid == 0) {
    float S = red[0] + red[1] + red[2] + red[3];
    float Q = red[8] + red[9] + red[10] + red[11];
    float mu = S * (1.f / 512.f);
    float var = Q * (1.f / 512.f) - mu * mu;
    red[16] = mu;
    red[17] = 1.f / sqrtf(var + 1e-5f);
  }
  __syncthreads();
  const float mu = red[16], rs = red[17];
  nbuf[tid] = (m0 - mu) * rs * ln_g[tid] + ln_b[tid];
  nbuf[tid + 256] = (m1 - mu) * rs * ln_g[tid + 256] + ln_b[tid + 256];
  __syncthreads();
  if (tid < 160) {
    const int o = tid >> 4, l = tid & 15;
    float p = 0.f;
    for (int w = l; w < 512; w += 16) p += nbuf[w] * beta_w[w * 10 + o];
    part[tid] = p;
  }
  __syncthreads();
  if (tid < 10) {
    float p = beta_b[tid];
#pragma unroll
    for (int l = 0; l < 16; ++l) p += part[tid * 16 + l];
    out[(size_t)b * 10 + tid] = p;
  }
}

// ---------------- k_pose (unchanged from round 0) ---------------------------
__global__ __launch_bounds__(512)
void k_pose(const float* __restrict__ h, const float* __restrict__ pw1,
            const float* __restrict__ pb1, const float* __restrict__ pw2,
            const float* __restrict__ pb2, float* __restrict__ out) {
  __shared__ float feat[16 * 1028];
  __shared__ float hid[16 * 513];
  __shared__ float p6[16 * 6];
  const int tid = threadIdx.x;
  const int j = blockIdx.y;
  const int bb0 = blockIdx.x * 16;
  const int par = KPAR_C[j];

  for (int idx = tid; idx < 16 * 1024; idx += 512) {
    const int gb = idx >> 10;
    const int c = idx & 1023;
    const int row = (c < 512) ? (j + 1) : par;
    feat[gb * 1028 + c] = h[((size_t)(bb0 + gb) * 22 + row) * 512 + (c & 511)];
  }
  __syncthreads();

  const float* w1 = pw1 + (size_t)j * (1024 * 512);
  float acc[16];
#pragma unroll
  for (int gb = 0; gb < 16; ++gb) acc[gb] = 0.f;

  for (int c = 0; c < 1024; c += 4) {
    float wa[4];
#pragma unroll
    for (int u = 0; u < 4; ++u) wa[u] = w1[(size_t)(c + u) * 512 + tid];
#pragma unroll
    for (int gb = 0; gb < 16; ++gb) {
      const float4 f = *(const float4*)&feat[gb * 1028 + c];
      acc[gb] = fmaf(f.x, wa[0], acc[gb]);
      acc[gb] = fmaf(f.y, wa[1], acc[gb]);
      acc[gb] = fmaf(f.z, wa[2], acc[gb]);
      acc[gb] = fmaf(f.w, wa[3], acc[gb]);
    }
  }
  const float bias1 = pb1[(size_t)j * 512 + tid];
#pragma unroll
  for (int gb = 0; gb < 16; ++gb) {
    float v = acc[gb] + bias1;
    hid[gb * 513 + tid] = v > 0.f ? v : 0.f;
  }
  __syncthreads();

  if (tid < 96) {
    const int gb = tid / 6;
    const int d = tid % 6;
    const float* w2 = pw2 + (size_t)j * (512 * 6) + d;
    float p = pb2[j * 6 + d];
    for (int hh = 0; hh < 512; ++hh) p = fmaf(hid[gb * 513 + hh], w2[hh * 6], p);
    p6[gb * 6 + d] = p;
    out[((size_t)(bb0 + gb) * 21 + j) * 6 + d] = p;
  }
  __syncthreads();
  if (tid < 16) {
    const int gb = tid;
    const float a1x = p6[gb * 6 + 0], a1y = p6[gb * 6 + 1], a1z = p6[gb * 6 + 2];
    const float a2x = p6[gb * 6 + 3], a2y = p6[gb * 6 + 4], a2z = p6[gb * 6 + 5];
    const float inv1 = 1.f / sqrtf(a1x * a1x + a1y * a1y + a1z * a1z);
    const float b1x = a1x * inv1, b1y = a1y * inv1, b1z = a1z * inv1;
    const float dot = b1x * a2x + b1y * a2y + b1z * a2z;
    const float px = a2x - dot * b1x, py = a2y - dot * b1y, pz = a2z - dot * b1z;
    const float inv2 = 1.f / sqrtf(px * px + py * py + pz * pz);
    const float b2x = px * inv2, b2y = py * inv2, b2z = pz * inv2;
    const float b3x = b1y * b2z - b1z * b2y;
    const float b3y = b1z * b2x - b1x * b2z;
    const float b3z = b1x * b2y - b1y * b2x;
    float* ro = out + 129024 + ((size_t)(bb0 + gb) * 21 + j) * 9;
    ro[0] = b1x; ro[1] = b1y; ro[2] = b1z;
    ro[3] = b2x; ro[4] = b2y; ro[5] = b2z;
    ro[6] = b3x; ro[7] = b3y; ro[8] = b3z;
  }
}

// ---------------- launch ----------------------------------------------------
extern "C" void kernel_launch(void* const* d_in, const int* in_sizes, int n_in,
                              void* d_out, int out_size, void* d_ws, size_t ws_size,
                              hipStream_t stream) {
  (void)in_sizes; (void)n_in; (void)out_size; (void)ws_size;
  const float* x       = (const float*)d_in[0];
  const float* conv1_w = (const float*)d_in[1];
  const float* conv1_b = (const float*)d_in[2];
  const float* tok_w   = (const float*)d_in[3];
  const float* tok_b   = (const float*)d_in[4];
  const float* up_w    = (const float*)d_in[5];
  const float* up_b    = (const float*)d_in[6];
  const float* ln_g    = (const float*)d_in[7];
  const float* ln_b    = (const float*)d_in[8];
  const float* beta_w  = (const float*)d_in[9];
  const float* beta_b  = (const float*)d_in[10];
  const float* pw1     = (const float*)d_in[11];
  const float* pb1     = (const float*)d_in[12];
  const float* pw2     = (const float*)d_in[13];
  const float* pb2     = (const float*)d_in[14];
  float* outp = (float*)d_out;

  char* base = (char*)d_ws;
  u16* WF  = (u16*)base;                      // 12,582,912 B
  u16* TWF = WF + 6291456;                    // 16,384 B
  u16* PA16 = (u16*)(base + 12599296);        // 134,217,728 B pool A
  u16* PB16 = (u16*)(base + 12599296 + 134217728);  // 104,857,600 B pool B
  // pool A: h1 planes -> a2 planes -> a3 planes -> h f32
  u16* h1hi = PA16;            u16* h1lo = PA16 + 33554432;
  u16* a2hi = PA16;            u16* a2lo = PA16 + 26214400;
  u16* a3hi = PA16;            u16* a3lo = PA16 + 18874368;
  float* hf = (float*)PA16;
  // pool B: g1 -> g2 -> g3
  u16* g1hi = PB16;            u16* g1lo = PB16 + 26214400;
  u16* g2hi = PB16;            u16* g2lo = PB16 + 18874368;
  u16* g3hi = PB16;            u16* g3lo = PB16 + 11534336;

  const size_t WL = 1572864;  // u16 per layer in WF

  kwprep<<<3076, 256, 0, stream>>>(conv1_w, up_w, tok_w, WF, TWF);
  conv_gemm<64, 64, true, false, true><<<dim3(2, 256), 512, 0, stream>>>(
      x, nullptr, nullptr, WF, conv1_b, h1hi, h1lo, nullptr);
  tok_mix<<<dim3(2, 1024), 512, 0, stream>>>(h1hi, h1lo, TWF, tok_b, g1hi, g1lo);
  conv_gemm<64, 50, false, false, true><<<dim3(2, 256), 512, 0, stream>>>(
      nullptr, g1hi, g1lo, WF + WL, up_b, a2hi, a2lo, nullptr);
  ginterp<36, 50><<<9216, 256, 0, stream>>>(a2hi, a2lo, g2hi, g2lo);
  conv_gemm<48, 36, false, false, true><<<dim3(2, 256), 512, 0, stream>>>(
      nullptr, g2hi, g2lo, WF + 2 * WL, up_b + 512, a3hi, a3lo, nullptr);
  ginterp<22, 36><<<5632, 256, 0, stream>>>(a3hi, a3lo, g3hi, g3lo);
  conv_gemm<32, 22, false, true, false><<<dim3(2, 256), 512, 0, stream>>>(
      nullptr, g3hi, g3lo, WF + 3 * WL, up_b + 1024, nullptr, nullptr, hf);
  k_beta<<<1024, 256, 0, stream>>>(hf, ln_g, ln_b, beta_w, beta_b, outp + 322560);
  k_pose<<<dim3(64, 21), 512, 0, stream>>>(hf, pw1, pb1, pw2, pb2, outp);
}

// Round 3
// 1253.466 us; speedup vs baseline: 4.4835x; 1.4996x over previous
//
#include <hip/hip_runtime.h>

// PoseSPDecoderKT — round 2: k_pose -> split-bf16 MFMA GEMM (kpw1prep + k_pose1
// + k_pose2). Conv stages unchanged from round 1.
// Split scheme everywhere: a = a_hi + a_lo (bf16 RNE), 3 MFMA products.
// LDS tiles in exact MFMA fragment order -> all frag reads ds_read_b128
// at base+lane*16 (optimal b128 pattern).

typedef unsigned short u16;
typedef unsigned short u16x4 __attribute__((ext_vector_type(4)));
typedef unsigned short u16x8 __attribute__((ext_vector_type(8)));
typedef float f32x4 __attribute__((ext_vector_type(4)));
typedef __bf16 bf16x8 __attribute__((ext_vector_type(8)));

__constant__ int KPAR_C[21] = {0,0,0,1,2,3,4,5,6,7,8,9,9,9,12,13,14,16,17,18,19};

__device__ __forceinline__ u16 bf16rne(float v) {
  unsigned b = __builtin_bit_cast(unsigned, v);
  return (u16)((b + 0x7fffu + ((b >> 16) & 1u)) >> 16);
}
__device__ __forceinline__ float bf16tof(u16 h) {
  unsigned b = ((unsigned)h) << 16;
  return __builtin_bit_cast(float, b);
}
__device__ __forceinline__ f32x4 mfma16(u16x8 a, u16x8 b, f32x4 c) {
  return __builtin_amdgcn_mfma_f32_16x16x32_bf16(
      __builtin_bit_cast(bf16x8, a), __builtin_bit_cast(bf16x8, b), c, 0, 0, 0);
}

// ---------------- kwprep: conv weights + tok_w -> fragment-order tiles ------
__global__ __launch_bounds__(256)
void kwprep(const float* __restrict__ conv1_w, const float* __restrict__ up_w,
            const float* __restrict__ tok_w, u16* __restrict__ WF, u16* __restrict__ TWF) {
  int idx = blockIdx.x * 256 + threadIdx.x;
  if (idx < 786432) {
    const int lane = idx & 63;
    int r = idx >> 6;
    const int nf = r & 15; r >>= 4;
    const int ks = r % 48; r /= 48;
    const int p = r & 1; r >>= 1;
    const int nh = r & 1;
    const int L = r >> 1;
    const float* Wsrc = (L == 0) ? conv1_w : (up_w + (size_t)(L - 1) * 786432);
    const int wcol = nh * 256 + nf * 16 + (lane & 15);
    u16x8 o;
#pragma unroll
    for (int e = 0; e < 8; ++e) {
      const int k = ks * 32 + ((lane >> 4) << 2) + (e & 3) + ((e >> 2) << 4);
      const int c = k & 511, kk = k >> 9;
      const float v = Wsrc[(size_t)wcol * 1536 + c * 3 + kk];
      const u16 h = bf16rne(v);
      o[e] = p ? bf16rne(v - bf16tof(h)) : h;
    }
    *(u16x8*)(WF + (size_t)idx * 8) = o;
  } else if (idx < 786432 + 1024) {
    const int i2 = idx - 786432;
    const int lane = i2 & 63;
    const int r = i2 >> 6;
    const int mf = r & 3;
    const int ks = (r >> 2) & 1;
    const int p = r >> 3;
    const int s = mf * 16 + (lane & 15);
    u16x8 o;
#pragma unroll
    for (int e = 0; e < 8; ++e) {
      const int t = ks * 32 + ((lane >> 4) << 2) + (e & 3) + ((e >> 2) << 4);
      const float v = tok_w[s * 64 + t];
      const u16 h = bf16rne(v);
      o[e] = p ? bf16rne(v - bf16tof(h)) : h;
    }
    *(u16x8*)(TWF + (size_t)i2 * 8) = o;
  }
}

// ---------------- kpw1prep: pw1 -> fragment-order split tiles ---------------
// PWF[((((j*2+nh)*2+p)*32+ks)*16+nf)*512 + lane*8 + e]
// col w = nh*256+nf*16+(lane&15); k = ks*32+((lane>>4)<<2)+(e&3)+((e>>2)<<4)
__global__ __launch_bounds__(256)
void kpw1prep(const float* __restrict__ pw1, u16* __restrict__ PWF) {
  const int idx = blockIdx.x * 256 + threadIdx.x;
  if (idx >= 2752512) return;
  const int lane = idx & 63;
  const int nf = (idx >> 6) & 15;
  const int ks = (idx >> 10) & 31;
  const int p = (idx >> 15) & 1;
  const int nh = (idx >> 16) & 1;
  const int j = idx >> 17;
  const int w = nh * 256 + nf * 16 + (lane & 15);
  u16x8 o;
#pragma unroll
  for (int e = 0; e < 8; ++e) {
    const int k = ks * 32 + ((lane >> 4) << 2) + (e & 3) + ((e >> 2) << 4);
    const float v = pw1[((size_t)j * 1024 + k) * 512 + w];
    const u16 h = bf16rne(v);
    o[e] = p ? bf16rne(v - bf16tof(h)) : h;
  }
  *(u16x8*)(PWF + (size_t)idx * 8) = o;
}

// ---------------- conv GEMM (unchanged from round 1) ------------------------
template <int SLOT, int ROWS, bool SRCF32, bool F32OUT, bool RELU>
__global__ __launch_bounds__(512, 2)
void conv_gemm(const float* __restrict__ xf,
               const u16* __restrict__ ghi, const u16* __restrict__ glo,
               const u16* __restrict__ wl,
               const float* __restrict__ bias,
               u16* __restrict__ ohi, u16* __restrict__ olo,
               float* __restrict__ of32) {
  constexpr int MFW = SLOT / 16;
  constexpr int MFT = 4 * MFW;
  constexpr int ASL = (MFT + 7) / 8;
  __shared__ u16x8 Ald[2][2][MFT][64];
  __shared__ u16x8 Bld[2][2][16][64];

  const int tid = threadIdx.x, lane = tid & 63, w = tid >> 6;
  const int mw = w & 3, nw = w >> 2;
  const int nh = blockIdx.x;
  const int bb0 = blockIdx.y * 4;

  f32x4 acc[MFW][8];
#pragma unroll
  for (int m = 0; m < MFW; ++m)
#pragma unroll
    for (int n = 0; n < 8; ++n) acc[m][n] = (f32x4){0.f, 0.f, 0.f, 0.f};

  float4 sF[ASL][2];
  u16x8 sH[ASL], sL[ASL];
  u16x8 sB[4];

  auto LOADS = [&](int ks2) {
    const int kk2 = ks2 >> 4;
    const int c0 = (ks2 & 15) * 32 + ((lane >> 4) << 2);
#pragma unroll
    for (int si = 0; si < ASL; ++si) {
      const int f = w + si * 8;
      if (f < MFT) {
        const int bA = f / MFW, mfA = f % MFW;
        int t = mfA * 16 + (lane & 15) - 1 + kk2;
        t = t < 0 ? 0 : (t > ROWS - 1 ? ROWS - 1 : t);
        const size_t o = ((size_t)(bb0 + bA) * ROWS + t) * 512 + c0;
        if constexpr (SRCF32) {
          sF[si][0] = *(const float4*)(xf + o);
          sF[si][1] = *(const float4*)(xf + o + 16);
        } else {
          const u16x4 a = *(const u16x4*)(ghi + o);
          const u16x4 b = *(const u16x4*)(ghi + o + 16);
          const u16x4 c = *(const u16x4*)(glo + o);
          const u16x4 d = *(const u16x4*)(glo + o + 16);
          sH[si] = (u16x8){a[0], a[1], a[2], a[3], b[0], b[1], b[2], b[3]};
          sL[si] = (u16x8){c[0], c[1], c[2], c[3], d[0], d[1], d[2], d[3]};
        }
      }
    }
#pragma unroll
    for (int ci = 0; ci < 4; ++ci) {
      const int cch = w + ci * 8;
      const int p = cch >> 4, nf = cch & 15;
      sB[ci] = *(const u16x8*)(wl + ((size_t)(((nh * 2 + p) * 48 + ks2) * 16 + nf)) * 512 + lane * 8);
    }
  };

  auto WRITES = [&](int nb) {
#pragma unroll
    for (int si = 0; si < ASL; ++si) {
      const int f = w + si * 8;
      if (f < MFT) {
        u16x8 hv, lv;
        if constexpr (SRCF32) {
          float vv[8] = {sF[si][0].x, sF[si][0].y, sF[si][0].z, sF[si][0].w,
                         sF[si][1].x, sF[si][1].y, sF[si][1].z, sF[si][1].w};
#pragma unroll
          for (int e = 0; e < 8; ++e) {
            const u16 h = bf16rne(vv[e]);
            hv[e] = h;
            lv[e] = bf16rne(vv[e] - bf16tof(h));
          }
        } else {
          hv = sH[si];
          lv = sL[si];
        }
        Ald[nb][0][f][lane] = hv;
        Ald[nb][1][f][lane] = lv;
      }
    }
#pragma unroll
    for (int ci = 0; ci < 4; ++ci) {
      const int cch = w + ci * 8;
      Bld[nb][cch >> 4][cch & 15][lane] = sB[ci];
    }
  };

  LOADS(0);
  WRITES(0);
  __syncthreads();

  for (int ks = 0; ks < 48; ++ks) {
    const int buf = ks & 1;
    if (ks < 47) LOADS(ks + 1);
    u16x8 ah[MFW], al[MFW];
#pragma unroll
    for (int m = 0; m < MFW; ++m) {
      ah[m] = Ald[buf][0][mw * MFW + m][lane];
      al[m] = Ald[buf][1][mw * MFW + m][lane];
    }
#pragma unroll
    for (int n = 0; n < 8; ++n) {
      const u16x8 bh = Bld[buf][0][nw * 8 + n][lane];
      const u16x8 bl = Bld[buf][1][nw * 8 + n][lane];
#pragma unroll
      for (int m = 0; m < MFW; ++m) {
        acc[m][n] = mfma16(ah[m], bh, acc[m][n]);
        acc[m][n] = mfma16(ah[m], bl, acc[m][n]);
        acc[m][n] = mfma16(al[m], bh, acc[m][n]);
      }
    }
    if (ks < 47) WRITES(buf ^ 1);
    __syncthreads();
  }

  const int b = bb0 + mw;
#pragma unroll
  for (int m = 0; m < MFW; ++m) {
#pragma unroll
    for (int n = 0; n < 8; ++n) {
      const int col = nh * 256 + nw * 128 + n * 16 + (lane & 15);
      const float bs = bias[col];
#pragma unroll
      for (int r = 0; r < 4; ++r) {
        const int t = m * 16 + ((lane >> 4) << 2) + r;
        if (t < ROWS) {
          float v = acc[m][n][r] + bs;
          if (RELU) v = fmaxf(v, 0.f);
          const size_t o = ((size_t)b * ROWS + t) * 512 + col;
          if constexpr (F32OUT) {
            of32[o] = v;
          } else {
            const u16 h = bf16rne(v);
            ohi[o] = h;
            olo[o] = bf16rne(v - bf16tof(h));
          }
        }
      }
    }
  }
}

// ---------------- tok_mix (unchanged from round 1) --------------------------
__global__ __launch_bounds__(512, 2)
void tok_mix(const u16* __restrict__ h1hi, const u16* __restrict__ h1lo,
             const u16* __restrict__ twf, const float* __restrict__ tok_b,
             u16* __restrict__ g1hi, u16* __restrict__ g1lo) {
  __shared__ float h1f[64][258];
  __shared__ u16x8 twl[2][2][4][64];
  __shared__ float tbl[64];
  const int tid = threadIdx.x, lane = tid & 63, w = tid >> 6;
  const int mw = w & 3, nw = w >> 2;
  const int b = blockIdx.y, ch = blockIdx.x;

  for (int i = tid; i < 1024; i += 512) ((u16x8*)twl)[i] = ((const u16x8*)twf)[i];
  if (tid < 64) tbl[tid] = tok_b[tid];
  for (int i = tid; i < 2048; i += 512) {
    const int t = i >> 5, c8 = (i & 31) * 8;
    const size_t o = ((size_t)b * 64 + t) * 512 + ch * 256 + c8;
    const u16x8 hv = *(const u16x8*)(h1hi + o);
    const u16x8 lv = *(const u16x8*)(h1lo + o);
#pragma unroll
    for (int e = 0; e < 8; ++e) h1f[t][c8 + e] = bf16tof(hv[e]) + bf16tof(lv[e]);
  }
  __syncthreads();

  f32x4 acc2[8];
#pragma unroll
  for (int n = 0; n < 8; ++n) acc2[n] = (f32x4){0.f, 0.f, 0.f, 0.f};
#pragma unroll
  for (int ksI = 0; ksI < 2; ++ksI) {
    const u16x8 ah = twl[0][ksI][mw][lane];
    const u16x8 al = twl[1][ksI][mw][lane];
    const int t0 = ksI * 32 + ((lane >> 4) << 2);
#pragma unroll
    for (int n = 0; n < 8; ++n) {
      const int c = nw * 128 + n * 16 + (lane & 15);
      u16x8 bh, bl;
#pragma unroll
      for (int e = 0; e < 8; ++e) {
        const float v = h1f[t0 + (e & 3) + ((e >> 2) << 4)][c];
        const u16 h = bf16rne(v);
        bh[e] = h;
        bl[e] = bf16rne(v - bf16tof(h));
      }
      acc2[n] = mfma16(ah, bh, acc2[n]);
      acc2[n] = mfma16(ah, bl, acc2[n]);
      acc2[n] = mfma16(al, bh, acc2[n]);
    }
  }
  __syncthreads();
#pragma unroll
  for (int n = 0; n < 8; ++n) {
    const int c = nw * 128 + n * 16 + (lane & 15);
#pragma unroll
    for (int r = 0; r < 4; ++r) {
      const int s = mw * 16 + ((lane >> 4) << 2) + r;
      h1f[s][c] = fmaxf(acc2[n][r] + tbl[s], 0.f);
    }
  }
  __syncthreads();
  const float scale = (float)(64.0 / 50.0);
  for (int i = tid; i < 50 * 256; i += 512) {
    const int s = i >> 8, c = i & 255;
    float coords = fminf(fmaxf(((float)s + 0.5f) * scale - 0.5f, 0.f), 63.f);
    const int lo = (int)floorf(coords);
    const int hi = lo + 1 < 64 ? lo + 1 : 63;
    const float wv = coords - (float)lo;
    const float v = h1f[lo][c] * (1.f - wv) + h1f[hi][c] * wv;
    const u16 h = bf16rne(v);
    const size_t o = ((size_t)b * 50 + s) * 512 + ch * 256 + c;
    g1hi[o] = h;
    g1lo[o] = bf16rne(v - bf16tof(h));
  }
}

// ---------------- ginterp (unchanged from round 1) --------------------------
template <int SOUT, int SIN>
__global__ __launch_bounds__(256)
void ginterp(const u16* __restrict__ ahi, const u16* __restrict__ alo,
             u16* __restrict__ ghi, u16* __restrict__ glo) {
  const int idx = blockIdx.x * 256 + threadIdx.x;
  if (idx >= 1024 * SOUT * 64) return;
  const int ch = (idx & 63) * 8;
  const int s = (idx >> 6) % SOUT;
  const int b = (idx >> 6) / SOUT;
  const float scale = (float)((double)SIN / (double)SOUT);
  float coords = fminf(fmaxf(((float)s + 0.5f) * scale - 0.5f, 0.f), (float)(SIN - 1));
  const int lo = (int)floorf(coords);
  const int hi = lo + 1 < SIN ? lo + 1 : SIN - 1;
  const float wv = coords - (float)lo;
  const size_t olo_ = ((size_t)b * SIN + lo) * 512 + ch;
  const size_t ohi_ = ((size_t)b * SIN + hi) * 512 + ch;
  const u16x8 vh0 = *(const u16x8*)(ahi + olo_), vl0 = *(const u16x8*)(alo + olo_);
  const u16x8 vh1 = *(const u16x8*)(ahi + ohi_), vl1 = *(const u16x8*)(alo + ohi_);
  u16x8 oh, ol;
#pragma unroll
  for (int e = 0; e < 8; ++e) {
    const float v0 = bf16tof(vh0[e]) + bf16tof(vl0[e]);
    const float v1 = bf16tof(vh1[e]) + bf16tof(vl1[e]);
    const float v = v0 * (1.f - wv) + v1 * wv;
    const u16 h = bf16rne(v);
    oh[e] = h;
    ol[e] = bf16rne(v - bf16tof(h));
  }
  const size_t oo = ((size_t)b * SOUT + s) * 512 + ch;
  *(u16x8*)(ghi + oo) = oh;
  *(u16x8*)(glo + oo) = ol;
}

// ---------------- k_beta (unchanged) ----------------------------------------
__global__ __launch_bounds__(256)
void k_beta(const float* __restrict__ h, const float* __restrict__ ln_g,
            const float* __restrict__ ln_b, const float* __restrict__ beta_w,
            const float* __restrict__ beta_b, float* __restrict__ out) {
  __shared__ float nbuf[512];
  __shared__ float red[32];
  __shared__ float part[160];
  const int tid = threadIdx.x;
  const int b = blockIdx.x;
  const float* hb = h + (size_t)b * (22 * 512);
  float m0 = 0.f, m1 = 0.f;
  for (int t = 0; t < 22; ++t) {
    m0 += hb[t * 512 + tid];
    m1 += hb[t * 512 + tid + 256];
  }
  m0 *= (1.f / 22.f);
  m1 *= (1.f / 22.f);
  float s = m0 + m1, sq = m0 * m0 + m1 * m1;
  for (int off = 32; off > 0; off >>= 1) {
    s += __shfl_down(s, off);
    sq += __shfl_down(sq, off);
  }
  const int lane = tid & 63, wid = tid >> 6;
  if (lane == 0) { red[wid] = s; red[8 + wid] = sq; }
  __syncthreads();
  if (tid == 0) {
    float S = red[0] + red[1] + red[2] + red[3];
    float Q = red[8] + red[9] + red[10] + red[11];
    float mu = S * (1.f / 512.f);
    float var = Q * (1.f / 512.f) - mu * mu;
    red[16] = mu;
    red[17] = 1.f / sqrtf(var + 1e-5f);
  }
  __syncthreads();
  const float mu = red[16], rs = red[17];
  nbuf[tid] = (m0 - mu) * rs * ln_g[tid] + ln_b[tid];
  nbuf[tid + 256] = (m1 - mu) * rs * ln_g[tid + 256] + ln_b[tid + 256];
  __syncthreads();
  if (tid < 160) {
    const int o = tid >> 4, l = tid & 15;
    float p = 0.f;
    for (int w = l; w < 512; w += 16) p += nbuf[w] * beta_w[w * 10 + o];
    part[tid] = p;
  }
  __syncthreads();
  if (tid < 10) {
    float p = beta_b[tid];
#pragma unroll
    for (int l = 0; l < 16; ++l) p += part[tid * 16 + l];
    out[(size_t)b * 10 + tid] = p;
  }
}

// ---------------- k_pose1: per-joint GEMM1 via MFMA -------------------------
// Grid: (nh*8+... x = mb*2+nh? -> x: [0,16), y: joint). Block 512 thr, 8 waves
// = 2 m-waves x 4 n-waves; wave tile 64 rows x 64 cols (4x4 frags).
// M=128 batches/block, N=256 cols (nh half), K=1024 (32 k-steps).
// A = feat rows from hf: k<512 -> row j+1 (curr), k>=512 -> row par (parent);
// k-step 16 is the exact boundary. Split on the fly. B from PWF tiles.
__global__ __launch_bounds__(512, 2)
void k_pose1(const float* __restrict__ hf, const u16* __restrict__ PWF,
             const float* __restrict__ pb1,
             u16* __restrict__ hidhi, u16* __restrict__ hidlo) {
  __shared__ u16x8 Ald[2][2][8][64];   // 32 KB
  __shared__ u16x8 Bld[2][2][16][64];  // 64 KB
  const int tid = threadIdx.x, lane = tid & 63, w = tid >> 6;
  const int mw = w & 1, nw = w >> 1;
  const int nh = blockIdx.x & 1, mb = blockIdx.x >> 1;
  const int j = blockIdx.y;
  const int bb0 = mb * 128;
  const int par = KPAR_C[j];
  const size_t pwbase = (size_t)(j * 2 + nh) * 524288;  // u16 units

  f32x4 acc[4][4];
#pragma unroll
  for (int m = 0; m < 4; ++m)
#pragma unroll
    for (int n = 0; n < 4; ++n) acc[m][n] = (f32x4){0.f, 0.f, 0.f, 0.f};

  float4 sF0, sF1;
  u16x8 sB[4];

  auto LOADS = [&](int ks) {
    const int row = (ks < 16) ? (j + 1) : par;
    const int b = bb0 + w * 16 + (lane & 15);
    const int c0 = (ks & 15) * 32 + ((lane >> 4) << 2);
    const float* src = hf + ((size_t)b * 22 + row) * 512 + c0;
    sF0 = *(const float4*)src;
    sF1 = *(const float4*)(src + 16);
#pragma unroll
    for (int t = 0; t < 4; ++t) {
      const int cc = t * 8 + w;
      const int p = cc >> 4, nf = cc & 15;
      sB[t] = *(const u16x8*)(PWF + pwbase + ((size_t)(p * 32 + ks) * 16 + nf) * 512 + lane * 8);
    }
  };
  auto WRITES = [&](int nb) {
    float vv[8] = {sF0.x, sF0.y, sF0.z, sF0.w, sF1.x, sF1.y, sF1.z, sF1.w};
    u16x8 hv, lv;
#pragma unroll
    for (int e = 0; e < 8; ++e) {
      const u16 h = bf16rne(vv[e]);
      hv[e] = h;
      lv[e] = bf16rne(vv[e] - bf16tof(h));
    }
    Ald[nb][0][w][lane] = hv;
    Ald[nb][1][w][lane] = lv;
#pragma unroll
    for (int t = 0; t < 4; ++t) {
      const int cc = t * 8 + w;
      Bld[nb][cc >> 4][cc & 15][lane] = sB[t];
    }
  };

  LOADS(0);
  WRITES(0);
  __syncthreads();

  for (int ks = 0; ks < 32; ++ks) {
    const int buf = ks & 1;
    if (ks < 31) LOADS(ks + 1);
    u16x8 ah[4], al[4], bh[4], bl[4];
#pragma unroll
    for (int m = 0; m < 4; ++m) {
      ah[m] = Ald[buf][0][mw * 4 + m][lane];
      al[m] = Ald[buf][1][mw * 4 + m][lane];
    }
#pragma unroll
    for (int n = 0; n < 4; ++n) {
      bh[n] = Bld[buf][0][nw * 4 + n][lane];
      bl[n] = Bld[buf][1][nw * 4 + n][lane];
    }
#pragma unroll
    for (int n = 0; n < 4; ++n)
#pragma unroll
      for (int m = 0; m < 4; ++m) {
        acc[m][n] = mfma16(ah[m], bh[n], acc[m][n]);
        acc[m][n] = mfma16(ah[m], bl[n], acc[m][n]);
        acc[m][n] = mfma16(al[m], bh[n], acc[m][n]);
      }
    if (ks < 31) WRITES(buf ^ 1);
    __syncthreads();
  }

  // epilogue: bias + relu -> split hid planes
#pragma unroll
  for (int m = 0; m < 4; ++m) {
#pragma unroll
    for (int n = 0; n < 4; ++n) {
      const int col = nh * 256 + nw * 64 + n * 16 + (lane & 15);
      const float bs = pb1[(size_t)j * 512 + col];
#pragma unroll
      for (int r = 0; r < 4; ++r) {
        const int b = bb0 + mw * 64 + m * 16 + ((lane >> 4) << 2) + r;
        float v = fmaxf(acc[m][n][r] + bs, 0.f);
        const size_t o = ((size_t)j * 1024 + b) * 512 + col;
        const u16 h = bf16rne(v);
        hidhi[o] = h;
        hidlo[o] = bf16rne(v - bf16tof(h));
      }
    }
  }
}

// ---------------- k_pose2: hid @ pw2 + rotmat -------------------------------
// Block = (128-batch chunk, joint). 256 threads: 2 per row (halves of K=512).
__global__ __launch_bounds__(256)
void k_pose2(const u16* __restrict__ hidhi, const u16* __restrict__ hidlo,
             const float* __restrict__ pw2, const float* __restrict__ pb2,
             float* __restrict__ out) {
  __shared__ float w2l[3072];
  __shared__ float part[128 * 12];
  const int tid = threadIdx.x;
  const int mb = blockIdx.x, j = blockIdx.y;
  const int bb0 = mb * 128;
  for (int i = tid; i < 3072; i += 256) w2l[i] = pw2[(size_t)j * 3072 + i];
  __syncthreads();

  const int r = tid >> 1, half = tid & 1;
  const int row = bb0 + r;
  const u16* ph = hidhi + ((size_t)j * 1024 + row) * 512 + half * 256;
  const u16* pl = hidlo + ((size_t)j * 1024 + row) * 512 + half * 256;
  float s[6] = {0.f, 0.f, 0.f, 0.f, 0.f, 0.f};
  for (int c = 0; c < 32; ++c) {
    const u16x8 hv = ((const u16x8*)ph)[c];
    const u16x8 lv = ((const u16x8*)pl)[c];
#pragma unroll
    for (int e = 0; e < 8; ++e) {
      const float v = bf16tof(hv[e]) + bf16tof(lv[e]);
      const int hidx = half * 256 + c * 8 + e;
#pragma unroll
      for (int d = 0; d < 6; ++d) s[d] = fmaf(v, w2l[hidx * 6 + d], s[d]);
    }
  }
#pragma unroll
  for (int d = 0; d < 6; ++d) part[r * 12 + half * 6 + d] = s[d];
  __syncthreads();

  if (tid < 128) {
    const int row2 = bb0 + tid;
    float p6[6];
#pragma unroll
    for (int d = 0; d < 6; ++d)
      p6[d] = part[tid * 12 + d] + part[tid * 12 + 6 + d] + pb2[j * 6 + d];
    float* po = out + ((size_t)row2 * 21 + j) * 6;
#pragma unroll
    for (int d = 0; d < 6; ++d) po[d] = p6[d];
    const float a1x = p6[0], a1y = p6[1], a1z = p6[2];
    const float a2x = p6[3], a2y = p6[4], a2z = p6[5];
    const float inv1 = 1.f / sqrtf(a1x * a1x + a1y * a1y + a1z * a1z);
    const float b1x = a1x * inv1, b1y = a1y * inv1, b1z = a1z * inv1;
    const float dot = b1x * a2x + b1y * a2y + b1z * a2z;
    const float px = a2x - dot * b1x, py = a2y - dot * b1y, pz = a2z - dot * b1z;
    const float inv2 = 1.f / sqrtf(px * px + py * py + pz * pz);
    const float b2x = px * inv2, b2y = py * inv2, b2z = pz * inv2;
    const float b3x = b1y * b2z - b1z * b2y;
    const float b3y = b1z * b2x - b1x * b2z;
    const float b3z = b1x * b2y - b1y * b2x;
    float* ro = out + 129024 + ((size_t)row2 * 21 + j) * 9;
    ro[0] = b1x; ro[1] = b1y; ro[2] = b1z;
    ro[3] = b2x; ro[4] = b2y; ro[5] = b2z;
    ro[6] = b3x; ro[7] = b3y; ro[8] = b3z;
  }
}

// ---------------- launch ----------------------------------------------------
extern "C" void kernel_launch(void* const* d_in, const int* in_sizes, int n_in,
                              void* d_out, int out_size, void* d_ws, size_t ws_size,
                              hipStream_t stream) {
  (void)in_sizes; (void)n_in; (void)out_size; (void)ws_size;
  const float* x       = (const float*)d_in[0];
  const float* conv1_w = (const float*)d_in[1];
  const float* conv1_b = (const float*)d_in[2];
  const float* tok_w   = (const float*)d_in[3];
  const float* tok_b   = (const float*)d_in[4];
  const float* up_w    = (const float*)d_in[5];
  const float* up_b    = (const float*)d_in[6];
  const float* ln_g    = (const float*)d_in[7];
  const float* ln_b    = (const float*)d_in[8];
  const float* beta_w  = (const float*)d_in[9];
  const float* beta_b  = (const float*)d_in[10];
  const float* pw1     = (const float*)d_in[11];
  const float* pb1     = (const float*)d_in[12];
  const float* pw2     = (const float*)d_in[13];
  const float* pb2     = (const float*)d_in[14];
  float* outp = (float*)d_out;

  char* base = (char*)d_ws;
  u16* WF  = (u16*)base;                            // 12,582,912 B
  u16* TWF = WF + 6291456;                          // 16,384 B
  u16* PA16 = (u16*)(base + 12599296);              // 134,217,728 B pool A
  u16* PB16 = (u16*)(base + 12599296 + 134217728);  // 104,857,600 B pool B
  // pool A: h1 planes -> a2 -> a3 -> hf (f32, 46 MB)
  u16* h1hi = PA16;            u16* h1lo = PA16 + 33554432;
  u16* a2hi = PA16;            u16* a2lo = PA16 + 26214400;
  u16* a3hi = PA16;            u16* a3lo = PA16 + 18874368;
  float* hf = (float*)PA16;
  // pool B: g1 -> g2 -> g3; after last conv_gemm all g dead ->
  //   PWF (22,020,096 u16) + hid planes (2 x 11,010,048 u16) = 44M u16 <= 52.4M
  u16* g1hi = PB16;            u16* g1lo = PB16 + 26214400;
  u16* g2hi = PB16;            u16* g2lo = PB16 + 18874368;
  u16* g3hi = PB16;            u16* g3lo = PB16 + 11534336;
  u16* PWF   = PB16;
  u16* hidhi = PB16 + 22020096;
  u16* hidlo = PB16 + 33030144;

  const size_t WL = 1572864;  // u16 per conv layer in WF

  kwprep<<<3076, 256, 0, stream>>>(conv1_w, up_w, tok_w, WF, TWF);
  conv_gemm<64, 64, true, false, true><<<dim3(2, 256), 512, 0, stream>>>(
      x, nullptr, nullptr, WF, conv1_b, h1hi, h1lo, nullptr);
  tok_mix<<<dim3(2, 1024), 512, 0, stream>>>(h1hi, h1lo, TWF, tok_b, g1hi, g1lo);
  conv_gemm<64, 50, false, false, true><<<dim3(2, 256), 512, 0, stream>>>(
      nullptr, g1hi, g1lo, WF + WL, up_b, a2hi, a2lo, nullptr);
  ginterp<36, 50><<<9216, 256, 0, stream>>>(a2hi, a2lo, g2hi, g2lo);
  conv_gemm<48, 36, false, false, true><<<dim3(2, 256), 512, 0, stream>>>(
      nullptr, g2hi, g2lo, WF + 2 * WL, up_b + 512, a3hi, a3lo, nullptr);
  ginterp<22, 36><<<5632, 256, 0, stream>>>(a3hi, a3lo, g3hi, g3lo);
  conv_gemm<32, 22, false, true, false><<<dim3(2, 256), 512, 0, stream>>>(
      nullptr, g3hi, g3lo, WF + 3 * WL, up_b + 1024, nullptr, nullptr, hf);
  // g planes dead -> build pose tiles in pool B
  kpw1prep<<<10752, 256, 0, stream>>>(pw1, PWF);
  k_pose1<<<dim3(16, 21), 512, 0, stream>>>(hf, PWF, pb1, hidhi, hidlo);
  k_beta<<<1024, 256, 0, stream>>>(hf, ln_g, ln_b, beta_w, beta_b, outp + 322560);
  k_pose2<<<dim3(8, 21), 256, 0, stream>>>(hidhi, hidlo, pw2, pb2, outp);
}